// Round 10
// baseline (171.226 us; speedup 1.0000x reference)
//
#include <hip/hip_runtime.h>
#include <hip/hip_bf16.h>
#include <math.h>

// Problem constants
#define BB 2
#define CC 64
#define HH 256
#define WW 256
#define OO 64
#define K2 9
#define HW 65536
#define CHW (CC*HW)

typedef _Float16 h8 __attribute__((ext_vector_type(8)));
typedef __fp16 fp16x2 __attribute__((ext_vector_type(2)));
typedef __attribute__((ext_vector_type(4))) unsigned int ux4;
typedef __attribute__((ext_vector_type(4))) float f32x4;

// Bijective XCD swizzle (nwg divisible by 8)
__device__ __forceinline__ int xcd_swz(int bid, int nwg) {
    const int per = nwg >> 3;
    return (bid & 7) * per + (bid >> 3);
}
__device__ __forceinline__ unsigned short f2h(float f) {
    _Float16 h = (_Float16)f;
    return __builtin_bit_cast(unsigned short, h);
}
__device__ __forceinline__ unsigned int pkrtz(float lo, float hi) {
    fp16x2 p = __builtin_amdgcn_cvt_pkrtz(lo, hi);
    return __builtin_bit_cast(unsigned int, p);
}
__device__ __forceinline__ h8 splat8(float f) {
    _Float16 h = (_Float16)f;
    h8 r = {h, h, h, h, h, h, h, h};
    return r;
}

// wA: [32 ch][576 s'] fp16, s' = tap*64 + c (tap-major K order). rows 27..31 = 0.
// wk: [9 k][64 o][64 c] fp16.
__global__ __launch_bounds__(256) void k_prep(
    const float* __restrict__ offw, const float* __restrict__ ampw,
    const float* __restrict__ w3d,
    unsigned short* __restrict__ wA, unsigned short* __restrict__ wk)
{
    int i = blockIdx.x * 256 + threadIdx.x;   // grid 216 -> 55296 exact
    if (i < 18432) {
        int ch = i / 576, sp = i % 576;
        int tap = sp >> 6, c = sp & 63;
        float v = 0.f;
        if (ch < 18)      v = offw[ch*576 + c*9 + tap];
        else if (ch < 27) v = ampw[(ch-18)*576 + c*9 + tap];
        wA[i] = f2h(v);
    } else if (i < 55296) {
        int j = i - 18432;
        int k = j >> 12, rem = j & 4095;
        int o = rem >> 6, c = rem & 63;
        wk[j] = f2h(w3d[o*576 + c*9 + k]);
    }
}

// Fused kernel. Block = 512 thr = 8 waves, owns (b, row-pair h0/h0+1, 64-col
// quarter), all 64 o. Tile = 6 rows x 68 cols x 64 c fp16 (52.2 KB) ->
// 2 blocks/CU = 4 waves/SIMD. Thread samples its own MFMA A-fragment; B-frags
// double-buffered across taps in registers; barrier-free tap loop.
__global__ __launch_bounds__(512, 4) void k_fused(
    const float* __restrict__ x, const unsigned short* __restrict__ wA,
    const unsigned short* __restrict__ wk,
    const float* __restrict__ offb, const float* __restrict__ ampb,
    float* __restrict__ out)
{
    // LDS map:
    //  tb  [0,52224)      : tile fp16, 408 planes (pp = rr*68+cc) x 128B (64 c),
    //                       16B-slot XOR-swizzled by (pp&7)
    //  ot16[52224,59352)  : conv+bias out fp16 [27 ch][132]
    //  epilogue: ct f32 [64][130] overlays tb.
    __shared__ __attribute__((aligned(16))) unsigned char lds[59360];
    unsigned char* tb = lds;
    _Float16* ot16 = (_Float16*)(lds + 52224);

    const int tid = threadIdx.x;
    const int idx = xcd_swz(blockIdx.x, BB*(HH/2)*4);   // 1024 blocks
    const int wq = idx & 3, hp = (idx >> 2) & 127, b = idx >> 9;
    const int h0 = hp << 1, w0 = wq << 6;
    const int lane = tid & 63, wv = tid >> 6;
    const int lrow = lane & 15, lg = lane >> 4;

    const float* xb = x + (size_t)b * CHW;
    const int r0a = h0 - 2, c0a = w0 - 2;

    // ---- Phase 1: stage tile (abs rows h0-2..h0+3, cols w0-2..w0+65, 0 outside).
    // One plane per thread; all 64 channel loads issued before packing.
    if (tid < 408) {
        const int rr = tid / 68;
        const int cc = tid - rr*68;
        const int ra = r0a + rr, ca = c0a + cc;
        const bool inb = ((unsigned)ra < 256u) && ((unsigned)ca < 256u);
        const float* ps = xb + ra*256 + ca;
        const int swz = (tid & 7) << 4;
        float v[64];
#pragma unroll
        for (int j = 0; j < 64; ++j)
            v[j] = inb ? ps[(size_t)j * HW] : 0.f;
#pragma unroll
        for (int s = 0; s < 8; ++s) {
            ux4 w;
#pragma unroll
            for (int t = 0; t < 4; ++t)
                w[t] = pkrtz(v[s*8 + 2*t], v[s*8 + 2*t + 1]);
            *(ux4*)(tb + tid*128 + ((s*16) ^ swz)) = w;
        }
    }
    __syncthreads();

    // ---- Phase 2: offset/amp conv via MFMA (fp16). D[m=ch(32)][n=px(16/wave)],
    // K=576. 8 waves cover 128 px.
    {
        f32x4 oacc0 = {0.f,0.f,0.f,0.f}, oacc1 = {0.f,0.f,0.f,0.f};
        const int pxl = wv*16 + lrow;           // 0..127
        const int prow = pxl >> 6, pcol = pxl & 63;
#pragma unroll
        for (int ks = 0; ks < 18; ++ks) {
            const int sbase = ks*32 + lg*8;
            const int tap = sbase >> 6;
            const int cb  = sbase & 63;
            const int ky = tap / 3, kx = tap - ky*3;
            const int pp = (prow + ky + 1)*68 + pcol + kx + 1;
            const h8 bf = *(const h8*)(tb + pp*128 + ((2*cb) ^ ((pp & 7) << 4)));
            const h8 a0 = *(const h8*)(wA + (      lrow)*576 + sbase);
            const h8 a1 = *(const h8*)(wA + (16 + lrow)*576 + sbase);
            oacc0 = __builtin_amdgcn_mfma_f32_16x16x32_f16(a0, bf, oacc0, 0, 0, 0);
            oacc1 = __builtin_amdgcn_mfma_f32_16x16x32_f16(a1, bf, oacc1, 0, 0, 0);
        }
#pragma unroll
        for (int r = 0; r < 4; ++r) {
            int ch0 = lg*4 + r;
            ot16[ch0*132 + pxl] = (_Float16)(oacc0[r] + offb[ch0]);
            int ch1 = 16 + lg*4 + r;
            if (ch1 < 27) {
                float bias = (ch1 < 18) ? offb[ch1] : ampb[ch1 - 18];
                ot16[ch1*132 + pxl] = (_Float16)(oacc1[r] + bias);
            }
        }
    }
    __syncthreads();

    // ---- Phase 3: barrier-free tap loop, B-frags double-buffered across taps.
    f32x4 acc[4];
#pragma unroll
    for (int n = 0; n < 4; ++n) acc[n] = (f32x4){0.f, 0.f, 0.f, 0.f};

    const int px = wv*16 + lrow;          // this thread's A-row pixel (0..127)
    const int prow = px >> 6, pcol = px & 63;
    const int cA0 = lg*8;                 // fallback c-chunk bases
    const int cA1 = 32 + lg*8;
    const int cb0 = lg*16;                // byte offsets within a 128B plane
    const int cb1 = 64 + lg*16;

    auto loadB = [&](int k, h8 f0[4], h8 f1[4]) {
        const unsigned short* wb = wk + (size_t)k*4096 + lg*8;
#pragma unroll
        for (int n = 0; n < 4; ++n) {
            f0[n] = *(const h8*)(wb + (n*16 + lrow)*64);
            f1[n] = *(const h8*)(wb + (n*16 + lrow)*64 + 32);
        }
    };

    auto tap_body = [&](int k, const h8 bf0[4], const h8 bf1[4]) {
        const int ky = k / 3, kx = k - ky*3;
        const float oy = (float)ot16[(2*k  )*132 + px];
        const float ox = (float)ot16[(2*k+1)*132 + px];
        const float az = (float)ot16[(18+k )*132 + px];
        float yy = (float)(h0 + prow + ky) + oy;
        float xx = (float)(w0 + pcol + kx) + ox;
        yy = fminf(fmaxf(yy, 0.f), 257.f);
        xx = fminf(fmaxf(xx, 0.f), 257.f);
        const float aa = 1.f / (1.f + __expf(-az));

        const float y0f = floorf(yy), x0f = floorf(xx);
        const float y1f = fminf(y0f + 1.f, 257.f);
        const float x1f = fminf(x0f + 1.f, 257.f);
        const float ay = yy - y0f, by = y1f - yy;
        const float ax = xx - x0f, bx = x1f - xx;
        const int r0 = (int)y0f - 1, r1 = (int)y1f - 1;
        const int c0 = (int)x0f - 1, c1 = (int)x1f - 1;
        const int rr0 = r0 - r0a, rr1 = r1 - r0a;
        const int cc0 = c0 - c0a, cc1 = c1 - c0a;
        const float w00 = by*bx*aa, w01 = by*ax*aa, w10 = ay*bx*aa, w11 = ay*ax*aa;

        h8 A0, A1;
        const bool ok = ((unsigned)rr0 <= 5u) && ((unsigned)rr1 <= 5u) &&
                        ((unsigned)cc0 <= 67u) && ((unsigned)cc1 <= 67u);
        if (ok) {
            const int pp00 = rr0*68 + cc0, pp01 = rr0*68 + cc1;
            const int pp10 = rr1*68 + cc0, pp11 = rr1*68 + cc1;
            const int s00 = (pp00 & 7) << 4, s01 = (pp01 & 7) << 4;
            const int s10 = (pp10 & 7) << 4, s11 = (pp11 & 7) << 4;
            const h8 Wb00 = splat8(w00), Wb01 = splat8(w01);
            const h8 Wb10 = splat8(w10), Wb11 = splat8(w11);

            auto bilerp8 = [&](int off) -> h8 {
                const h8 d00 = *(const h8*)(tb + pp00*128 + (off ^ s00));
                const h8 d01 = *(const h8*)(tb + pp01*128 + (off ^ s01));
                const h8 d10 = *(const h8*)(tb + pp10*128 + (off ^ s10));
                const h8 d11 = *(const h8*)(tb + pp11*128 + (off ^ s11));
                h8 t = d00 * Wb00;
                t = __builtin_elementwise_fma(d01, Wb01, t);
                t = __builtin_elementwise_fma(d10, Wb10, t);
                t = __builtin_elementwise_fma(d11, Wb11, t);
                return t;
            };
            A0 = bilerp8(cb0);
            A1 = bilerp8(cb1);
        } else {
            const bool vy0 = (unsigned)r0 < 256u, vy1 = (unsigned)r1 < 256u;
            const bool vx0 = (unsigned)c0 < 256u, vx1 = (unsigned)c1 < 256u;
            float W00 = w00, W01 = w01, W10 = w10, W11 = w11;
            int o00, o01, o10, o11;
            if (vy0 && vx0) o00 = r0*WW + c0; else { o00 = 0; W00 = 0.f; }
            if (vy0 && vx1) o01 = r0*WW + c1; else { o01 = 0; W01 = 0.f; }
            if (vy1 && vx0) o10 = r1*WW + c0; else { o10 = 0; W10 = 0.f; }
            if (vy1 && vx1) o11 = r1*WW + c1; else { o11 = 0; W11 = 0.f; }
            const float* pc0 = xb + (size_t)cA0 * HW;
            const float* pc1 = xb + (size_t)cA1 * HW;
#pragma unroll
            for (int jj = 0; jj < 8; ++jj) {
                float va = W00*pc0[o00] + W01*pc0[o01] + W10*pc0[o10] + W11*pc0[o11];
                pc0 += HW;
                A0[jj] = (_Float16)va;
                float vb = W00*pc1[o00] + W01*pc1[o01] + W10*pc1[o10] + W11*pc1[o11];
                pc1 += HW;
                A1[jj] = (_Float16)vb;
            }
        }

#pragma unroll
        for (int n = 0; n < 4; ++n)
            acc[n] = __builtin_amdgcn_mfma_f32_16x16x32_f16(A0, bf0[n], acc[n], 0, 0, 0);
#pragma unroll
        for (int n = 0; n < 4; ++n)
            acc[n] = __builtin_amdgcn_mfma_f32_16x16x32_f16(A1, bf1[n], acc[n], 0, 0, 0);
    };

    h8 e0[4], e1[4], o0[4], o1[4];
    loadB(0, e0, e1);
#pragma unroll 1
    for (int k = 0; k < 8; k += 2) {
        loadB(k + 1, o0, o1);       // prefetch odd tap
        tap_body(k, e0, e1);
        loadB(k + 2, e0, e1);       // prefetch next even tap (k+2 <= 8)
        tap_body(k + 1, o0, o1);
    }
    tap_body(8, e0, e1);

    // ---- Epilogue: transpose via LDS (overlays tile) -> coalesced ReLU stores
    __syncthreads();
    float* ct = (float*)lds;    // [64 o][130]
#pragma unroll
    for (int n = 0; n < 4; ++n)
#pragma unroll
        for (int r = 0; r < 4; ++r)
            ct[(n*16 + lrow)*130 + wv*16 + lg*4 + r] = acc[n][r];
    __syncthreads();

    const size_t ob = (size_t)b*OO*HW + (size_t)h0*WW + w0;
#pragma unroll
    for (int it = 0; it < 16; ++it) {
        const int o = it*4 + (wv & 3);
        const int row = wv >> 2;
        out[ob + (size_t)o*HW + row*WW + lane] =
            fmaxf(ct[o*130 + row*64 + lane], 0.f);
    }
}

extern "C" void kernel_launch(void* const* d_in, const int* in_sizes, int n_in,
                              void* d_out, int out_size, void* d_ws, size_t ws_size,
                              hipStream_t stream) {
    const float* x    = (const float*)d_in[0];
    const float* offw = (const float*)d_in[1];
    const float* offb = (const float*)d_in[2];
    const float* ampw = (const float*)d_in[3];
    const float* ampb = (const float*)d_in[4];
    const float* w3d  = (const float*)d_in[5];
    float* out = (float*)d_out;

    unsigned short* wA = (unsigned short*)d_ws;          // 18432 fp16
    unsigned short* wk = wA + 18432;                     // 36864 fp16

    k_prep<<<216, 256, 0, stream>>>(offw, ampw, w3d, wA, wk);
    k_fused<<<BB*(HH/2)*4, 512, 0, stream>>>(x, wA, wk, offb, ampb, out);
}

// Round 11
// 125.227 us; speedup vs baseline: 1.3673x; 1.3673x over previous
//
#include <hip/hip_runtime.h>
#include <hip/hip_bf16.h>
#include <math.h>

// Problem constants
#define BB 2
#define CC 64
#define HH 256
#define WW 256
#define OO 64
#define K2 9
#define HW 65536
#define CHW (CC*HW)

typedef _Float16 h8 __attribute__((ext_vector_type(8)));
typedef __fp16 fp16x2 __attribute__((ext_vector_type(2)));
typedef __attribute__((ext_vector_type(4))) unsigned int ux4;
typedef __attribute__((ext_vector_type(4))) float f32x4;

// Bijective XCD swizzle (nwg divisible by 8)
__device__ __forceinline__ int xcd_swz(int bid, int nwg) {
    const int per = nwg >> 3;
    return (bid & 7) * per + (bid >> 3);
}
__device__ __forceinline__ unsigned short f2h(float f) {
    _Float16 h = (_Float16)f;
    return __builtin_bit_cast(unsigned short, h);
}
__device__ __forceinline__ unsigned int pkrtz(float lo, float hi) {
    fp16x2 p = __builtin_amdgcn_cvt_pkrtz(lo, hi);
    return __builtin_bit_cast(unsigned int, p);
}
__device__ __forceinline__ h8 splat8(float f) {
    _Float16 h = (_Float16)f;
    h8 r = {h, h, h, h, h, h, h, h};
    return r;
}

// wA: [32 ch][576 s'] fp16, s' = tap*64 + c (tap-major K order). rows 27..31 = 0.
// wk: [9 k][64 o][64 c] fp16.
__global__ __launch_bounds__(256) void k_prep(
    const float* __restrict__ offw, const float* __restrict__ ampw,
    const float* __restrict__ w3d,
    unsigned short* __restrict__ wA, unsigned short* __restrict__ wk)
{
    int i = blockIdx.x * 256 + threadIdx.x;   // grid 216 -> 55296 exact
    if (i < 18432) {
        int ch = i / 576, sp = i % 576;
        int tap = sp >> 6, c = sp & 63;
        float v = 0.f;
        if (ch < 18)      v = offw[ch*576 + c*9 + tap];
        else if (ch < 27) v = ampw[(ch-18)*576 + c*9 + tap];
        wA[i] = f2h(v);
    } else if (i < 55296) {
        int j = i - 18432;
        int k = j >> 12, rem = j & 4095;
        int o = rem >> 6, c = rem & 63;
        wk[j] = f2h(w3d[o*576 + c*9 + k]);
    }
}

// Fused kernel. Block = 512 thr = 8 waves, owns (b, row-pair h0/h0+1, 64-col
// quarter), all 64 o. Tile = 6 rows x 68 cols x 64 c fp16 (52.2 KB) ->
// 2 blocks/CU = 4 waves/SIMD. Register-lean (no big arrays) to avoid spill.
__global__ __launch_bounds__(512, 4) void k_fused(
    const float* __restrict__ x, const unsigned short* __restrict__ wA,
    const unsigned short* __restrict__ wk,
    const float* __restrict__ offb, const float* __restrict__ ampb,
    float* __restrict__ out)
{
    // LDS map:
    //  tb  [0,52224)      : tile fp16, 408 planes (pp = rr*68+cc) x 128B (64 c),
    //                       16B-slot XOR-swizzled by (pp&7)
    //  ot16[52224,59352)  : conv+bias out fp16 [27 ch][132]
    //  epilogue: ct f32 [64][130] overlays tb.
    __shared__ __attribute__((aligned(16))) unsigned char lds[59360];
    unsigned char* tb = lds;
    _Float16* ot16 = (_Float16*)(lds + 52224);

    const int tid = threadIdx.x;
    const int idx = xcd_swz(blockIdx.x, BB*(HH/2)*4);   // 1024 blocks
    const int wq = idx & 3, hp = (idx >> 2) & 127, b = idx >> 9;
    const int h0 = hp << 1, w0 = wq << 6;
    const int lane = tid & 63, wv = tid >> 6;
    const int lrow = lane & 15, lg = lane >> 4;

    const float* xb = x + (size_t)b * CHW;
    const int r0a = h0 - 2, c0a = w0 - 2;

    // ---- Phase 1: stage tile (abs rows h0-2..h0+3, cols w0-2..w0+65, 0 outside).
    // One plane per thread; channels in 4 chunks of 16 (register-lean).
    if (tid < 408) {
        const int rr = tid / 68;
        const int cc = tid - rr*68;
        const int ra = r0a + rr, ca = c0a + cc;
        const bool inb = ((unsigned)ra < 256u) && ((unsigned)ca < 256u);
        const float* ps = xb + ra*256 + ca;
        const int swz = (tid & 7) << 4;
#pragma unroll
        for (int ch = 0; ch < 64; ch += 16) {
            float v[16];
#pragma unroll
            for (int j = 0; j < 16; ++j)
                v[j] = inb ? ps[(size_t)(ch + j) * HW] : 0.f;
            ux4 q0, q1;
            q0[0] = pkrtz(v[0],  v[1]);
            q0[1] = pkrtz(v[2],  v[3]);
            q0[2] = pkrtz(v[4],  v[5]);
            q0[3] = pkrtz(v[6],  v[7]);
            q1[0] = pkrtz(v[8],  v[9]);
            q1[1] = pkrtz(v[10], v[11]);
            q1[2] = pkrtz(v[12], v[13]);
            q1[3] = pkrtz(v[14], v[15]);
            *(ux4*)(tb + tid*128 + ((ch*2     ) ^ swz)) = q0;
            *(ux4*)(tb + tid*128 + ((ch*2 + 16) ^ swz)) = q1;
        }
    }
    __syncthreads();

    // ---- Phase 2: offset/amp conv via MFMA (fp16). D[m=ch(32)][n=px(16/wave)],
    // K=576. 8 waves cover 128 px.
    {
        f32x4 oacc0 = {0.f,0.f,0.f,0.f}, oacc1 = {0.f,0.f,0.f,0.f};
        const int pxl = wv*16 + lrow;           // 0..127
        const int prow2 = pxl >> 6, pcol2 = pxl & 63;
#pragma unroll
        for (int ks = 0; ks < 18; ++ks) {
            const int sbase = ks*32 + lg*8;
            const int tap = sbase >> 6;
            const int cb  = sbase & 63;
            const int ky = tap / 3, kx = tap - ky*3;
            const int pp = (prow2 + ky + 1)*68 + pcol2 + kx + 1;
            const h8 bf = *(const h8*)(tb + pp*128 + ((2*cb) ^ ((pp & 7) << 4)));
            const h8 a0 = *(const h8*)(wA + (      lrow)*576 + sbase);
            const h8 a1 = *(const h8*)(wA + (16 + lrow)*576 + sbase);
            oacc0 = __builtin_amdgcn_mfma_f32_16x16x32_f16(a0, bf, oacc0, 0, 0, 0);
            oacc1 = __builtin_amdgcn_mfma_f32_16x16x32_f16(a1, bf, oacc1, 0, 0, 0);
        }
#pragma unroll
        for (int r = 0; r < 4; ++r) {
            int ch0 = lg*4 + r;
            ot16[ch0*132 + pxl] = (_Float16)(oacc0[r] + offb[ch0]);
            int ch1 = 16 + lg*4 + r;
            if (ch1 < 27) {
                float bias = (ch1 < 18) ? offb[ch1] : ampb[ch1 - 18];
                ot16[ch1*132 + pxl] = (_Float16)(oacc1[r] + bias);
            }
        }
    }
    __syncthreads();

    // ---- Phase 3: barrier-free tap loop (single B-buffer, register-lean).
    f32x4 acc[4];
#pragma unroll
    for (int n = 0; n < 4; ++n) acc[n] = (f32x4){0.f, 0.f, 0.f, 0.f};

    const int px = wv*16 + lrow;          // this thread's A-row pixel (0..127)
    const int prow = px >> 6, pcol = px & 63;
    const int cA0 = lg*8;                 // fallback c-chunk bases
    const int cA1 = 32 + lg*8;
    const int cb0 = lg*16;                // byte offsets within a 128B plane
    const int cb1 = 64 + lg*16;

#pragma unroll 3
    for (int k = 0; k < K2; ++k) {
        // B-fragments for tap k, directly from global (L2-resident 8KB slice)
        h8 bf0[4], bf1[4];
        {
            const unsigned short* wb = wk + (size_t)k*4096 + lg*8;
#pragma unroll
            for (int n = 0; n < 4; ++n) {
                bf0[n] = *(const h8*)(wb + (n*16 + lrow)*64);
                bf1[n] = *(const h8*)(wb + (n*16 + lrow)*64 + 32);
            }
        }

        // sampling params for (px, tap k)
        const int ky = k / 3, kx = k - ky*3;
        const float oy = (float)ot16[(2*k  )*132 + px];
        const float ox = (float)ot16[(2*k+1)*132 + px];
        const float az = (float)ot16[(18+k )*132 + px];
        float yy = (float)(h0 + prow + ky) + oy;
        float xx = (float)(w0 + pcol + kx) + ox;
        yy = fminf(fmaxf(yy, 0.f), 257.f);
        xx = fminf(fmaxf(xx, 0.f), 257.f);
        const float aa = 1.f / (1.f + __expf(-az));

        const float y0f = floorf(yy), x0f = floorf(xx);
        const float y1f = fminf(y0f + 1.f, 257.f);
        const float x1f = fminf(x0f + 1.f, 257.f);
        const float ay = yy - y0f, by = y1f - yy;
        const float ax = xx - x0f, bx = x1f - xx;
        const int r0 = (int)y0f - 1, r1 = (int)y1f - 1;
        const int c0 = (int)x0f - 1, c1 = (int)x1f - 1;
        const int rr0 = r0 - r0a, rr1 = r1 - r0a;
        const int cc0 = c0 - c0a, cc1 = c1 - c0a;
        const float w00 = by*bx*aa, w01 = by*ax*aa, w10 = ay*bx*aa, w11 = ay*ax*aa;

        h8 A0, A1;
        const bool ok = ((unsigned)rr0 <= 5u) && ((unsigned)rr1 <= 5u) &&
                        ((unsigned)cc0 <= 67u) && ((unsigned)cc1 <= 67u);
        if (ok) {
            const int pp00 = rr0*68 + cc0, pp01 = rr0*68 + cc1;
            const int pp10 = rr1*68 + cc0, pp11 = rr1*68 + cc1;
            const int s00 = (pp00 & 7) << 4, s01 = (pp01 & 7) << 4;
            const int s10 = (pp10 & 7) << 4, s11 = (pp11 & 7) << 4;
            const h8 Wb00 = splat8(w00), Wb01 = splat8(w01);
            const h8 Wb10 = splat8(w10), Wb11 = splat8(w11);

            auto bilerp8 = [&](int off) -> h8 {
                const h8 d00 = *(const h8*)(tb + pp00*128 + (off ^ s00));
                const h8 d01 = *(const h8*)(tb + pp01*128 + (off ^ s01));
                const h8 d10 = *(const h8*)(tb + pp10*128 + (off ^ s10));
                const h8 d11 = *(const h8*)(tb + pp11*128 + (off ^ s11));
                h8 t = d00 * Wb00;
                t = __builtin_elementwise_fma(d01, Wb01, t);
                t = __builtin_elementwise_fma(d10, Wb10, t);
                t = __builtin_elementwise_fma(d11, Wb11, t);
                return t;
            };
            A0 = bilerp8(cb0);
            A1 = bilerp8(cb1);
        } else {
            const bool vy0 = (unsigned)r0 < 256u, vy1 = (unsigned)r1 < 256u;
            const bool vx0 = (unsigned)c0 < 256u, vx1 = (unsigned)c1 < 256u;
            float W00 = w00, W01 = w01, W10 = w10, W11 = w11;
            int o00, o01, o10, o11;
            if (vy0 && vx0) o00 = r0*WW + c0; else { o00 = 0; W00 = 0.f; }
            if (vy0 && vx1) o01 = r0*WW + c1; else { o01 = 0; W01 = 0.f; }
            if (vy1 && vx0) o10 = r1*WW + c0; else { o10 = 0; W10 = 0.f; }
            if (vy1 && vx1) o11 = r1*WW + c1; else { o11 = 0; W11 = 0.f; }
            const float* pc0 = xb + (size_t)cA0 * HW;
            const float* pc1 = xb + (size_t)cA1 * HW;
#pragma unroll
            for (int jj = 0; jj < 8; ++jj) {
                float va = W00*pc0[o00] + W01*pc0[o01] + W10*pc0[o10] + W11*pc0[o11];
                pc0 += HW;
                A0[jj] = (_Float16)va;
                float vb = W00*pc1[o00] + W01*pc1[o01] + W10*pc1[o10] + W11*pc1[o11];
                pc1 += HW;
                A1[jj] = (_Float16)vb;
            }
        }

        // MFMA tap k: A-frags straight from registers
#pragma unroll
        for (int n = 0; n < 4; ++n)
            acc[n] = __builtin_amdgcn_mfma_f32_16x16x32_f16(A0, bf0[n], acc[n], 0, 0, 0);
#pragma unroll
        for (int n = 0; n < 4; ++n)
            acc[n] = __builtin_amdgcn_mfma_f32_16x16x32_f16(A1, bf1[n], acc[n], 0, 0, 0);
    }

    // ---- Epilogue: transpose via LDS (overlays tile) -> coalesced ReLU stores
    __syncthreads();
    float* ct = (float*)lds;    // [64 o][130]
#pragma unroll
    for (int n = 0; n < 4; ++n)
#pragma unroll
        for (int r = 0; r < 4; ++r)
            ct[(n*16 + lrow)*130 + wv*16 + lg*4 + r] = acc[n][r];
    __syncthreads();

    const size_t ob = (size_t)b*OO*HW + (size_t)h0*WW + w0;
#pragma unroll
    for (int it = 0; it < 16; ++it) {
        const int o = it*4 + (wv & 3);
        const int row = wv >> 2;
        out[ob + (size_t)o*HW + row*WW + lane] =
            fmaxf(ct[o*130 + row*64 + lane], 0.f);
    }
}

extern "C" void kernel_launch(void* const* d_in, const int* in_sizes, int n_in,
                              void* d_out, int out_size, void* d_ws, size_t ws_size,
                              hipStream_t stream) {
    const float* x    = (const float*)d_in[0];
    const float* offw = (const float*)d_in[1];
    const float* offb = (const float*)d_in[2];
    const float* ampw = (const float*)d_in[3];
    const float* ampb = (const float*)d_in[4];
    const float* w3d  = (const float*)d_in[5];
    float* out = (float*)d_out;

    unsigned short* wA = (unsigned short*)d_ws;          // 18432 fp16
    unsigned short* wk = wA + 18432;                     // 36864 fp16

    k_prep<<<216, 256, 0, stream>>>(offw, ampw, w3d, wA, wk);
    k_fused<<<BB*(HH/2)*4, 512, 0, stream>>>(x, wA, wk, offb, ampb, out);
}

// Round 13
// 120.695 us; speedup vs baseline: 1.4187x; 1.0376x over previous
//
#include <hip/hip_runtime.h>
#include <hip/hip_bf16.h>
#include <math.h>

// Problem constants
#define BB 2
#define CC 64
#define HH 256
#define WW 256
#define OO 64
#define K2 9
#define HW 65536
#define CHW (CC*HW)

typedef _Float16 h8 __attribute__((ext_vector_type(8)));
typedef __fp16 fp16x2 __attribute__((ext_vector_type(2)));
typedef __attribute__((ext_vector_type(4))) unsigned int ux4;
typedef __attribute__((ext_vector_type(4))) float f32x4;

// Bijective XCD swizzle (nwg divisible by 8)
__device__ __forceinline__ int xcd_swz(int bid, int nwg) {
    const int per = nwg >> 3;
    return (bid & 7) * per + (bid >> 3);
}
__device__ __forceinline__ unsigned short f2h(float f) {
    _Float16 h = (_Float16)f;
    return __builtin_bit_cast(unsigned short, h);
}
__device__ __forceinline__ unsigned int pkrtz(float lo, float hi) {
    fp16x2 p = __builtin_amdgcn_cvt_pkrtz(lo, hi);
    return __builtin_bit_cast(unsigned int, p);
}
__device__ __forceinline__ h8 splat8(float f) {
    _Float16 h = (_Float16)f;
    h8 r = {h, h, h, h, h, h, h, h};
    return r;
}

// wA: [32 ch][576 s'] fp16, s' = tap*64 + c (tap-major K order). rows 27..31 = 0.
// wk: [9 k][64 o][64 c] fp16.
__global__ __launch_bounds__(256) void k_prep(
    const float* __restrict__ offw, const float* __restrict__ ampw,
    const float* __restrict__ w3d,
    unsigned short* __restrict__ wA, unsigned short* __restrict__ wk)
{
    int i = blockIdx.x * 256 + threadIdx.x;   // grid 216 -> 55296 exact
    if (i < 18432) {
        int ch = i / 576, sp = i % 576;
        int tap = sp >> 6, c = sp & 63;
        float v = 0.f;
        if (ch < 18)      v = offw[ch*576 + c*9 + tap];
        else if (ch < 27) v = ampw[(ch-18)*576 + c*9 + tap];
        wA[i] = f2h(v);
    } else if (i < 55296) {
        int j = i - 18432;
        int k = j >> 12, rem = j & 4095;
        int o = rem >> 6, c = rem & 63;
        wk[j] = f2h(w3d[o*576 + c*9 + k]);
    }
}

// Fused kernel. Block = 512 thr = 8 waves, owns (b, row-pair h0/h0+1, 64-col
// quarter), all 64 o. Tile = 6 rows x 68 cols x 64 c fp16 (52.2 KB) ->
// 2 blocks/CU. R11 structure + hoisted per-tap offset/amp registers and a
// fully-unrolled tap loop (static indexing).
__global__ __launch_bounds__(512, 4) void k_fused(
    const float* __restrict__ x, const unsigned short* __restrict__ wA,
    const unsigned short* __restrict__ wk,
    const float* __restrict__ offb, const float* __restrict__ ampb,
    float* __restrict__ out)
{
    // LDS map:
    //  tb  [0,52224)      : tile fp16, 408 planes (pp = rr*68+cc) x 128B (64 c),
    //                       16B-slot XOR-swizzled by (pp&7)
    //  ot16[52224,59352)  : conv+bias out fp16 [27 ch][132]
    //  epilogue: ct f32 [64][130] overlays tb.
    __shared__ __attribute__((aligned(16))) unsigned char lds[59360];
    unsigned char* tb = lds;
    _Float16* ot16 = (_Float16*)(lds + 52224);

    const int tid = threadIdx.x;
    const int idx = xcd_swz(blockIdx.x, BB*(HH/2)*4);   // 1024 blocks
    const int wq = idx & 3, hp = (idx >> 2) & 127, b = idx >> 9;
    const int h0 = hp << 1, w0 = wq << 6;
    const int lane = tid & 63, wv = tid >> 6;
    const int lrow = lane & 15, lg = lane >> 4;

    const float* xb = x + (size_t)b * CHW;
    const int r0a = h0 - 2, c0a = w0 - 2;

    // ---- Phase 1: stage tile (abs rows h0-2..h0+3, cols w0-2..w0+65, 0 outside).
    // One plane per thread; channels in 4 chunks of 16 (register-lean).
    if (tid < 408) {
        const int rr = tid / 68;
        const int cc = tid - rr*68;
        const int ra = r0a + rr, ca = c0a + cc;
        const bool inb = ((unsigned)ra < 256u) && ((unsigned)ca < 256u);
        const float* ps = xb + ra*256 + ca;
        const int swz = (tid & 7) << 4;
#pragma unroll
        for (int ch = 0; ch < 64; ch += 16) {
            float v[16];
#pragma unroll
            for (int j = 0; j < 16; ++j)
                v[j] = inb ? ps[(size_t)(ch + j) * HW] : 0.f;
            ux4 q0, q1;
            q0[0] = pkrtz(v[0],  v[1]);
            q0[1] = pkrtz(v[2],  v[3]);
            q0[2] = pkrtz(v[4],  v[5]);
            q0[3] = pkrtz(v[6],  v[7]);
            q1[0] = pkrtz(v[8],  v[9]);
            q1[1] = pkrtz(v[10], v[11]);
            q1[2] = pkrtz(v[12], v[13]);
            q1[3] = pkrtz(v[14], v[15]);
            *(ux4*)(tb + tid*128 + ((ch*2     ) ^ swz)) = q0;
            *(ux4*)(tb + tid*128 + ((ch*2 + 16) ^ swz)) = q1;
        }
    }
    __syncthreads();

    // ---- Phase 2: offset/amp conv via MFMA (fp16). D[m=ch(32)][n=px(16/wave)],
    // K=576. 8 waves cover 128 px.
    {
        f32x4 oacc0 = {0.f,0.f,0.f,0.f}, oacc1 = {0.f,0.f,0.f,0.f};
        const int pxl = wv*16 + lrow;           // 0..127
        const int prow2 = pxl >> 6, pcol2 = pxl & 63;
#pragma unroll
        for (int ks = 0; ks < 18; ++ks) {
            const int sbase = ks*32 + lg*8;
            const int tap = sbase >> 6;
            const int cb  = sbase & 63;
            const int ky = tap / 3, kx = tap - ky*3;
            const int pp = (prow2 + ky + 1)*68 + pcol2 + kx + 1;
            const h8 bf = *(const h8*)(tb + pp*128 + ((2*cb) ^ ((pp & 7) << 4)));
            const h8 a0 = *(const h8*)(wA + (      lrow)*576 + sbase);
            const h8 a1 = *(const h8*)(wA + (16 + lrow)*576 + sbase);
            oacc0 = __builtin_amdgcn_mfma_f32_16x16x32_f16(a0, bf, oacc0, 0, 0, 0);
            oacc1 = __builtin_amdgcn_mfma_f32_16x16x32_f16(a1, bf, oacc1, 0, 0, 0);
        }
#pragma unroll
        for (int r = 0; r < 4; ++r) {
            int ch0 = lg*4 + r;
            ot16[ch0*132 + pxl] = (_Float16)(oacc0[r] + offb[ch0]);
            int ch1 = 16 + lg*4 + r;
            if (ch1 < 27) {
                float bias = (ch1 < 18) ? offb[ch1] : ampb[ch1 - 18];
                ot16[ch1*132 + pxl] = (_Float16)(oacc1[r] + bias);
            }
        }
    }
    __syncthreads();

    // ---- Phase 3 prologue: hoist per-tap offsets/amp into registers
    // (one LDS batch instead of 27 chain-head reads spread over the loop).
    const int px = wv*16 + lrow;          // this thread's A-row pixel (0..127)
    const int prow = px >> 6, pcol = px & 63;
    const int cA0 = lg*8;                 // fallback c-chunk bases
    const int cA1 = 32 + lg*8;
    const int cb0 = lg*16;                // byte offsets within a 128B plane
    const int cb1 = 64 + lg*16;

    float oyv[K2], oxv[K2], aav[K2];
#pragma unroll
    for (int k = 0; k < K2; ++k) {
        oyv[k] = (float)ot16[(2*k  )*132 + px];
        oxv[k] = (float)ot16[(2*k+1)*132 + px];
        const float az = (float)ot16[(18+k )*132 + px];
        aav[k] = 1.f / (1.f + __expf(-az));
    }

    // ---- Phase 3: fully-unrolled tap loop; head is register-only.
    f32x4 acc[4];
#pragma unroll
    for (int n = 0; n < 4; ++n) acc[n] = (f32x4){0.f, 0.f, 0.f, 0.f};

#pragma unroll
    for (int k = 0; k < K2; ++k) {
        // B-fragments for tap k, directly from global (L2-resident 8KB slice)
        h8 bf0[4], bf1[4];
        {
            const unsigned short* wb = wk + (size_t)k*4096 + lg*8;
#pragma unroll
            for (int n = 0; n < 4; ++n) {
                bf0[n] = *(const h8*)(wb + (n*16 + lrow)*64);
                bf1[n] = *(const h8*)(wb + (n*16 + lrow)*64 + 32);
            }
        }

        // sampling params for (px, tap k) — inputs already in registers
        const int ky = k / 3, kx = k - ky*3;
        const float aa = aav[k];
        float yy = (float)(h0 + prow + ky) + oyv[k];
        float xx = (float)(w0 + pcol + kx) + oxv[k];
        yy = fminf(fmaxf(yy, 0.f), 257.f);
        xx = fminf(fmaxf(xx, 0.f), 257.f);

        const float y0f = floorf(yy), x0f = floorf(xx);
        const float y1f = fminf(y0f + 1.f, 257.f);
        const float x1f = fminf(x0f + 1.f, 257.f);
        const float ay = yy - y0f, by = y1f - yy;
        const float ax = xx - x0f, bx = x1f - xx;
        const int r0 = (int)y0f - 1, r1 = (int)y1f - 1;
        const int c0 = (int)x0f - 1, c1 = (int)x1f - 1;
        const int rr0 = r0 - r0a, rr1 = r1 - r0a;
        const int cc0 = c0 - c0a, cc1 = c1 - c0a;
        const float w00 = by*bx*aa, w01 = by*ax*aa, w10 = ay*bx*aa, w11 = ay*ax*aa;

        h8 A0, A1;
        const bool ok = ((unsigned)rr0 <= 5u) && ((unsigned)rr1 <= 5u) &&
                        ((unsigned)cc0 <= 67u) && ((unsigned)cc1 <= 67u);
        if (ok) {
            const int pp00 = rr0*68 + cc0, pp01 = rr0*68 + cc1;
            const int pp10 = rr1*68 + cc0, pp11 = rr1*68 + cc1;
            const int s00 = (pp00 & 7) << 4, s01 = (pp01 & 7) << 4;
            const int s10 = (pp10 & 7) << 4, s11 = (pp11 & 7) << 4;
            const h8 Wb00 = splat8(w00), Wb01 = splat8(w01);
            const h8 Wb10 = splat8(w10), Wb11 = splat8(w11);

            auto bilerp8 = [&](int off) -> h8 {
                const h8 d00 = *(const h8*)(tb + pp00*128 + (off ^ s00));
                const h8 d01 = *(const h8*)(tb + pp01*128 + (off ^ s01));
                const h8 d10 = *(const h8*)(tb + pp10*128 + (off ^ s10));
                const h8 d11 = *(const h8*)(tb + pp11*128 + (off ^ s11));
                h8 t = d00 * Wb00;
                t = __builtin_elementwise_fma(d01, Wb01, t);
                t = __builtin_elementwise_fma(d10, Wb10, t);
                t = __builtin_elementwise_fma(d11, Wb11, t);
                return t;
            };
            A0 = bilerp8(cb0);
            A1 = bilerp8(cb1);
        } else {
            const bool vy0 = (unsigned)r0 < 256u, vy1 = (unsigned)r1 < 256u;
            const bool vx0 = (unsigned)c0 < 256u, vx1 = (unsigned)c1 < 256u;
            float W00 = w00, W01 = w01, W10 = w10, W11 = w11;
            int o00, o01, o10, o11;
            if (vy0 && vx0) o00 = r0*WW + c0; else { o00 = 0; W00 = 0.f; }
            if (vy0 && vx1) o01 = r0*WW + c1; else { o01 = 0; W01 = 0.f; }
            if (vy1 && vx0) o10 = r1*WW + c0; else { o10 = 0; W10 = 0.f; }
            if (vy1 && vx1) o11 = r1*WW + c1; else { o11 = 0; W11 = 0.f; }
            const float* pc0 = xb + (size_t)cA0 * HW;
            const float* pc1 = xb + (size_t)cA1 * HW;
#pragma unroll
            for (int jj = 0; jj < 8; ++jj) {
                float va = W00*pc0[o00] + W01*pc0[o01] + W10*pc0[o10] + W11*pc0[o11];
                pc0 += HW;
                A0[jj] = (_Float16)va;
                float vb = W00*pc1[o00] + W01*pc1[o01] + W10*pc1[o10] + W11*pc1[o11];
                pc1 += HW;
                A1[jj] = (_Float16)vb;
            }
        }

        // MFMA tap k: A-frags straight from registers
#pragma unroll
        for (int n = 0; n < 4; ++n)
            acc[n] = __builtin_amdgcn_mfma_f32_16x16x32_f16(A0, bf0[n], acc[n], 0, 0, 0);
#pragma unroll
        for (int n = 0; n < 4; ++n)
            acc[n] = __builtin_amdgcn_mfma_f32_16x16x32_f16(A1, bf1[n], acc[n], 0, 0, 0);
    }

    // ---- Epilogue: transpose via LDS (overlays tile) -> coalesced ReLU stores
    __syncthreads();
    float* ct = (float*)lds;    // [64 o][130]
#pragma unroll
    for (int n = 0; n < 4; ++n)
#pragma unroll
        for (int r = 0; r < 4; ++r)
            ct[(n*16 + lrow)*130 + wv*16 + lg*4 + r] = acc[n][r];
    __syncthreads();

    const size_t ob = (size_t)b*OO*HW + (size_t)h0*WW + w0;
#pragma unroll
    for (int it = 0; it < 16; ++it) {
        const int o = it*4 + (wv & 3);
        const int row = wv >> 2;
        out[ob + (size_t)o*HW + row*WW + lane] =
            fmaxf(ct[o*130 + row*64 + lane], 0.f);
    }
}

extern "C" void kernel_launch(void* const* d_in, const int* in_sizes, int n_in,
                              void* d_out, int out_size, void* d_ws, size_t ws_size,
                              hipStream_t stream) {
    const float* x    = (const float*)d_in[0];
    const float* offw = (const float*)d_in[1];
    const float* offb = (const float*)d_in[2];
    const float* ampw = (const float*)d_in[3];
    const float* ampb = (const float*)d_in[4];
    const float* w3d  = (const float*)d_in[5];
    float* out = (float*)d_out;

    unsigned short* wA = (unsigned short*)d_ws;          // 18432 fp16
    unsigned short* wk = wA + 18432;                     // 36864 fp16

    k_prep<<<216, 256, 0, stream>>>(offw, ampw, w3d, wA, wk);
    k_fused<<<BB*(HH/2)*4, 512, 0, stream>>>(x, wA, wk, offb, ampb, out);
}